// Round 11
// baseline (23.942 us; speedup 1.0000x reference)
//
#include <hip/hip_runtime.h>

#define BB 384   // batch
#define DD 128   // embedding dim
#define NI 3     // number of losses
#define SS 25    // seq len in target
#define APB 4    // anchors per block (288 blocks, proven best occupancy)
#define BPI (BB / APB)         // 96 blocks per i
#define GRID (NI * BPI)        // 288
#define PSTRIDE 128            // padded partial stride per i

// ---------------------------------------------------------------------------
// Kernel 1: per block = (i, 4 consecutive anchors).
//  - wave 0 computes anchor norms pre-B1 (vector loads + shuffle reduce),
//    so the dot->distance path needs no extra barrier (3 barriers total).
//  - anchors read via block-uniform pointer -> scalar loads in the dot loop.
//  - own row fully unrolled (compiler hoists all 32 float4 loads).
//  - positives compacted into dense per-anchor lists; block pre-sums 4
//    anchors' (tot,cnt) into one partial slot; plain stores, no atomics.
// ---------------------------------------------------------------------------
__global__ __launch_bounds__(384) void triplet_kernel(
    const float* __restrict__ vr,          // [NI, BB, DD]
    const float* __restrict__ target,      // [BB, SS, NI]
    const int*   __restrict__ label_item,  // [BB]
    float* __restrict__ part_T,            // [NI * PSTRIDE]
    int*   __restrict__ part_C)            // [NI * PSTRIDE]
{
    const int blk  = blockIdx.x;           // 0 .. GRID-1
    const int i    = blk / BPI;            // uniform (SGPR)
    const int b    = blk % BPI;
    const int a0   = b * APB;
    const int t    = threadIdx.x;          // 0 .. 383
    const int lane = t & 63;
    const int wid  = t >> 6;               // 0 .. 5

    __shared__ float aas[APB];             // ||x_{a_k}||^2
    __shared__ float dp_seg[APB][BB];      // dense positive-distance lists
    __shared__ int   wp[6][APB];           // per-wave positive counts
    __shared__ float labs2[BB];            // i=2 only
    __shared__ float rf[6];
    __shared__ int   ri[6];

    // ---- wave 0: anchor norms (vector loads, 4 interleaved reduces) ----
    if (wid == 0) {
        const float* axf = vr + ((size_t)i * BB + a0) * DD;
        float s[APB];
        #pragma unroll
        for (int k = 0; k < APB; ++k) {
            const float v0 = axf[k * DD + lane];
            const float v1 = axf[k * DD + lane + 64];
            s[k] = fmaf(v0, v0, v1 * v1);
        }
        #pragma unroll
        for (int off = 32; off > 0; off >>= 1) {
            #pragma unroll
            for (int k = 0; k < APB; ++k) s[k] += __shfl_down(s[k], off, 64);
        }
        if (lane == 0) {
            #pragma unroll
            for (int k = 0; k < APB; ++k) aas[k] = s[k];
        }
    }

    // ---- classification per anchor ----
    bool isPos[APB], isNeg[APB];
    if (i < 2) {
        const int li_t = label_item[t];
        #pragma unroll
        for (int k = 0; k < APB; ++k) {
            const int li_a = label_item[a0 + k];   // uniform -> scalar load
            isPos[k] = (li_t == li_a) && (t != a0 + k);
            isNeg[k] = (li_t != li_a);
        }
    } else {
        float m = 0.0f;
        const float* tp = target + (size_t)t * (SS * NI) + 2;
        #pragma unroll
        for (int s = 0; s < SS; ++s) m += tp[s * NI];
        m *= (1.0f / (float)SS);
        labs2[t] = m;
        __syncthreads();
        #pragma unroll
        for (int k = 0; k < APB; ++k) {
            const float la = labs2[a0 + k];
            isPos[k] = (m == la) && (t != a0 + k);
            isNeg[k] = (m != la);
        }
    }

    // in-wave compaction ranks per anchor
    int rp[APB];
    const unsigned long long lowmask =
        (lane == 0) ? 0ull : (~0ull >> (64 - lane));
    #pragma unroll
    for (int k = 0; k < APB; ++k) {
        const unsigned long long mpk = __ballot(isPos[k]);
        rp[k] = __popcll(mpk & lowmask);
        if (lane == 0) wp[wid][k] = __popcll(mpk);
    }
    __syncthreads();                       // B1: wp, aas (and labs2) visible

    // block-level dense offsets + totals per anchor (registers, no barrier)
    int P[APB], posBase[APB];
    #pragma unroll
    for (int k = 0; k < APB; ++k) {
        P[k] = 0; posBase[k] = 0;
        #pragma unroll
        for (int w = 0; w < 6; ++w) {
            if (w < wid) posBase[k] += wp[w][k];
            P[k] += wp[w][k];
        }
    }
    const int Pany = P[0] + P[1] + P[2] + P[3];
    if (Pany == 0) {                       // block-uniform (all i=2 blocks a.s.)
        if (t == 0) { part_T[i * PSTRIDE + b] = 0.0f; part_C[i * PSTRIDE + b] = 0; }
        return;
    }

    // ---- 4 dots + own-row norm; fully unrolled (loads hoisted) ----
    const float4* xb  = (const float4*)(vr + ((size_t)i * BB + t) * DD);
    const float4* axp = (const float4*)(vr + ((size_t)i * BB + a0) * DD);
    // packed-pair accumulators (invite v_pk_fma_f32)
    float2 ab0p = {0.f, 0.f}, ab1p = {0.f, 0.f}, ab2p = {0.f, 0.f},
           ab3p = {0.f, 0.f}, bbp = {0.f, 0.f};
    #pragma unroll
    for (int c = 0; c < DD / 4; ++c) {
        const float4 bv  = xb[c];
        const float4 a0v = axp[c];                  // uniform -> SGPRs
        const float4 a1v = axp[(DD / 4) + c];
        const float4 a2v = axp[2 * (DD / 4) + c];
        const float4 a3v = axp[3 * (DD / 4) + c];
        ab0p.x = fmaf(a0v.x, bv.x, ab0p.x); ab0p.y = fmaf(a0v.y, bv.y, ab0p.y);
        ab0p.x = fmaf(a0v.z, bv.z, ab0p.x); ab0p.y = fmaf(a0v.w, bv.w, ab0p.y);
        ab1p.x = fmaf(a1v.x, bv.x, ab1p.x); ab1p.y = fmaf(a1v.y, bv.y, ab1p.y);
        ab1p.x = fmaf(a1v.z, bv.z, ab1p.x); ab1p.y = fmaf(a1v.w, bv.w, ab1p.y);
        ab2p.x = fmaf(a2v.x, bv.x, ab2p.x); ab2p.y = fmaf(a2v.y, bv.y, ab2p.y);
        ab2p.x = fmaf(a2v.z, bv.z, ab2p.x); ab2p.y = fmaf(a2v.w, bv.w, ab2p.y);
        ab3p.x = fmaf(a3v.x, bv.x, ab3p.x); ab3p.y = fmaf(a3v.y, bv.y, ab3p.y);
        ab3p.x = fmaf(a3v.z, bv.z, ab3p.x); ab3p.y = fmaf(a3v.w, bv.w, ab3p.y);
        bbp.x  = fmaf(bv.x,  bv.x, bbp.x ); bbp.y  = fmaf(bv.y,  bv.y, bbp.y );
        bbp.x  = fmaf(bv.z,  bv.z, bbp.x ); bbp.y  = fmaf(bv.w,  bv.w, bbp.y );
    }
    const float bb = bbp.x + bbp.y;
    const float ab[APB] = { ab0p.x + ab0p.y, ab1p.x + ab1p.y,
                            ab2p.x + ab2p.y, ab3p.x + ab3p.y };

    // d^2 = 2 - 2*cos (unit-norm rows; approx err ~1e-6 << 0.037 threshold)
    const float invb = rsqrtf(fmaxf(bb, 1e-24f));
    float d[APB];
    #pragma unroll
    for (int k = 0; k < APB; ++k) {
        const float inva = rsqrtf(fmaxf(aas[k], 1e-24f));   // ready since B1
        const float cosv = ab[k] * (inva * invb);
        d[k] = sqrtf(fmaxf(fmaf(-2.0f, cosv, 2.0f), 0.0f));
        if (isPos[k]) dp_seg[k][posBase[k] + rp[k]] = d[k];
    }
    __syncthreads();                       // B2: dp_seg visible

    // sweep: each negative thread scans the dense positive list per anchor
    float tot = 0.0f;
    int   cnt = 0;
    #pragma unroll
    for (int k = 0; k < APB; ++k) {
        if (isNeg[k]) {
            const float ck  = 1.0f - d[k];         // term = ck + seg[p]
            const float* seg = dp_seg[k];
            const int    Pk  = P[k];
            #pragma unroll 4
            for (int p = 0; p < Pk; ++p) {
                const float term = ck + seg[p];
                if (term > 0.0f && term < 1.0f) { cnt += 1; tot += term; }
            }
        }
    }
    #pragma unroll
    for (int off = 32; off > 0; off >>= 1) {
        tot += __shfl_down(tot, off, 64);
        cnt += __shfl_down(cnt, off, 64);
    }
    if (lane == 0) { rf[wid] = tot; ri[wid] = cnt; }
    __syncthreads();                       // B3
    if (t == 0) {
        float T = 0.0f; int C = 0;
        #pragma unroll
        for (int w = 0; w < 6; ++w) { T += rf[w]; C += ri[w]; }
        part_T[i * PSTRIDE + b] = T;
        part_C[i * PSTRIDE + b] = C;
    }
}

// ---------------------------------------------------------------------------
// Kernel 2: 192 threads = 3 waves; wave j reduces loss j (96 partials,
// 2 per lane). 1 barrier, 4 outputs.
// ---------------------------------------------------------------------------
__global__ __launch_bounds__(192) void finalize_kernel(
    const float* __restrict__ part_T,
    const int*   __restrict__ part_C,
    float* __restrict__ out)
{
    const int t    = threadIdx.x;
    const int lane = t & 63;
    const int j    = t >> 6;       // 0..2 (loss index)
    __shared__ float rf[3];
    __shared__ int   ri[3];

    float T = part_T[j * PSTRIDE + lane] + part_T[j * PSTRIDE + lane + 64];
    int   C = part_C[j * PSTRIDE + lane] + part_C[j * PSTRIDE + lane + 64];
    // lanes 32..63 of the second half are padding (BPI=96 => lane+64 < 128 ok,
    // slots 96..127 are zero-initialized by the triplet kernel? NO — use mask)
    if (lane + 64 >= BPI) {
        T = part_T[j * PSTRIDE + lane];
        C = part_C[j * PSTRIDE + lane];
    }
    #pragma unroll
    for (int off = 32; off > 0; off >>= 1) {
        T += __shfl_down(T, off, 64);
        C += __shfl_down(C, off, 64);
    }
    if (lane == 0) { rf[j] = T; ri[j] = C; }
    __syncthreads();
    if (t == 0) {
        float lsum = 0.0f;
        #pragma unroll
        for (int k = 0; k < NI; ++k) {
            const float lk = (ri[k] > 0) ? (rf[k] / (float)ri[k]) : 0.0f;
            out[1 + k] = lk;
            lsum += lk;
        }
        out[0] = lsum;
    }
}

extern "C" void kernel_launch(void* const* d_in, const int* in_sizes, int n_in,
                              void* d_out, int out_size, void* d_ws, size_t ws_size,
                              hipStream_t stream) {
    const float* vr         = (const float*)d_in[1];
    const float* target     = (const float*)d_in[2];
    const int*   label_item = (const int*)d_in[4];
    float* out = (float*)d_out;

    float* part_T = (float*)d_ws;                  // NI*PSTRIDE floats
    int*   part_C = (int*)(part_T + NI * PSTRIDE); // NI*PSTRIDE ints

    triplet_kernel<<<GRID, 384, 0, stream>>>(vr, target, label_item,
                                             part_T, part_C);
    finalize_kernel<<<1, 192, 0, stream>>>(part_T, part_C, out);
}

// Round 12
// 21.940 us; speedup vs baseline: 1.0913x; 1.0913x over previous
//
#include <hip/hip_runtime.h>

#define BB 384   // batch
#define DD 128   // embedding dim
#define NI 3     // number of losses
#define SS 25    // seq len in target
#define APB 4    // anchors per block (288 blocks ~ 1.1/CU, proven best: R6/R9/R10)
#define BPI (BB / APB)         // 96 blocks per i
#define GRID (NI * BPI)        // 288
#define PSTRIDE 128            // padded partial stride per i

// ---------------------------------------------------------------------------
// Kernel 1 (R10-proven best): per block = (i, 4 consecutive anchors). Anchor
// rows are read via a BLOCK-UNIFORM pointer -> scalar loads (SGPRs), so the
// dot loop is v_fma(v, s, v) with no LDS traffic. Each thread owns row t,
// loads it once (float4), computes 4 dots. Anchor norms free (thread t==a_k
// publishes own-row norm from the dot loop's bb). Positives compacted into
// dense per-anchor lists. Block pre-sums 4 anchors' (tot,cnt) into one
// partial slot; plain stores, no atomics, no fences (kernel-boundary sync).
// ---------------------------------------------------------------------------
__global__ __launch_bounds__(384) void triplet_kernel(
    const float* __restrict__ vr,          // [NI, BB, DD]
    const float* __restrict__ target,      // [BB, SS, NI]
    const int*   __restrict__ label_item,  // [BB]
    float* __restrict__ part_T,            // [NI * PSTRIDE]
    int*   __restrict__ part_C)            // [NI * PSTRIDE]
{
    const int blk  = blockIdx.x;           // 0 .. GRID-1
    const int i    = blk / BPI;            // uniform (SGPR)
    const int b    = blk % BPI;
    const int a0   = b * APB;
    const int t    = threadIdx.x;          // 0 .. 383
    const int lane = t & 63;
    const int wid  = t >> 6;               // 0 .. 5

    __shared__ float aas[APB];             // ||x_{a_k}||^2
    __shared__ float dp_seg[APB][BB];      // dense positive-distance lists
    __shared__ int   wp[6][APB];           // per-wave positive counts
    __shared__ float labs2[BB];            // i=2 only
    __shared__ float rf[6];
    __shared__ int   ri[6];

    // block-uniform anchor base pointer (scalar loads in the dot loop)
    const float4* axp = (const float4*)(vr + ((size_t)i * BB + a0) * DD);

    // classification per anchor
    bool isPos[APB], isNeg[APB];
    if (i < 2) {
        const int li_t = label_item[t];
        #pragma unroll
        for (int k = 0; k < APB; ++k) {
            const int li_a = label_item[a0 + k];   // uniform -> scalar load
            isPos[k] = (li_t == li_a) && (t != a0 + k);
            isNeg[k] = (li_t != li_a);
        }
    } else {
        float m = 0.0f;
        const float* tp = target + (size_t)t * (SS * NI) + 2;
        #pragma unroll
        for (int s = 0; s < SS; ++s) m += tp[s * NI];
        m *= (1.0f / (float)SS);
        labs2[t] = m;
        __syncthreads();
        #pragma unroll
        for (int k = 0; k < APB; ++k) {
            const float la = labs2[a0 + k];
            isPos[k] = (m == la) && (t != a0 + k);
            isNeg[k] = (m != la);
        }
    }

    // in-wave compaction ranks per anchor
    int rp[APB];
    const unsigned long long lowmask =
        (lane == 0) ? 0ull : (~0ull >> (64 - lane));
    #pragma unroll
    for (int k = 0; k < APB; ++k) {
        const unsigned long long mpk = __ballot(isPos[k]);
        rp[k] = __popcll(mpk & lowmask);
        if (lane == 0) wp[wid][k] = __popcll(mpk);
    }
    __syncthreads();                       // B1: wp (and labs2) visible

    // block-level dense offsets + totals per anchor (registers, no barrier)
    int P[APB], posBase[APB];
    #pragma unroll
    for (int k = 0; k < APB; ++k) {
        P[k] = 0; posBase[k] = 0;
        #pragma unroll
        for (int w = 0; w < 6; ++w) {
            if (w < wid) posBase[k] += wp[w][k];
            P[k] += wp[w][k];
        }
    }
    const int Pany = P[0] + P[1] + P[2] + P[3];
    if (Pany == 0) {                       // block-uniform (all i=2 blocks a.s.)
        if (t == 0) { part_T[i * PSTRIDE + b] = 0.0f; part_C[i * PSTRIDE + b] = 0; }
        return;
    }

    // 4 dots + own-row squared norm; own row float4 (vector), anchors scalar
    const float4* xb = (const float4*)(vr + ((size_t)i * BB + t) * DD);
    float ab0 = 0.0f, ab1 = 0.0f, ab2 = 0.0f, ab3 = 0.0f, bb = 0.0f;
    #pragma unroll 4
    for (int c = 0; c < DD / 4; ++c) {
        const float4 bv  = xb[c];
        const float4 a0v = axp[c];                  // uniform -> SGPRs
        const float4 a1v = axp[(DD / 4) + c];
        const float4 a2v = axp[2 * (DD / 4) + c];
        const float4 a3v = axp[3 * (DD / 4) + c];
        ab0 = fmaf(a0v.x, bv.x, ab0); ab0 = fmaf(a0v.y, bv.y, ab0);
        ab0 = fmaf(a0v.z, bv.z, ab0); ab0 = fmaf(a0v.w, bv.w, ab0);
        ab1 = fmaf(a1v.x, bv.x, ab1); ab1 = fmaf(a1v.y, bv.y, ab1);
        ab1 = fmaf(a1v.z, bv.z, ab1); ab1 = fmaf(a1v.w, bv.w, ab1);
        ab2 = fmaf(a2v.x, bv.x, ab2); ab2 = fmaf(a2v.y, bv.y, ab2);
        ab2 = fmaf(a2v.z, bv.z, ab2); ab2 = fmaf(a2v.w, bv.w, ab2);
        ab3 = fmaf(a3v.x, bv.x, ab3); ab3 = fmaf(a3v.y, bv.y, ab3);
        ab3 = fmaf(a3v.z, bv.z, ab3); ab3 = fmaf(a3v.w, bv.w, ab3);
        bb  = fmaf(bv.x,  bv.x, bb ); bb  = fmaf(bv.y,  bv.y, bb );
        bb  = fmaf(bv.z,  bv.z, bb ); bb  = fmaf(bv.w,  bv.w, bb );
    }
    // anchor a_k IS row a_k: its thread publishes bb as the anchor norm
    if (t >= a0 && t < a0 + APB) aas[t - a0] = bb;
    __syncthreads();                       // B2: aas visible

    // d^2 = 2 - 2*cos (unit-norm rows; approx err ~1e-6 << 0.037 threshold)
    const float invb = rsqrtf(fmaxf(bb, 1e-24f));
    const float ab[APB] = { ab0, ab1, ab2, ab3 };
    float d[APB];
    #pragma unroll
    for (int k = 0; k < APB; ++k) {
        const float inva = rsqrtf(fmaxf(aas[k], 1e-24f));
        const float cosv = ab[k] * (inva * invb);
        d[k] = sqrtf(fmaxf(fmaf(-2.0f, cosv, 2.0f), 0.0f));
        if (isPos[k]) dp_seg[k][posBase[k] + rp[k]] = d[k];
    }
    __syncthreads();                       // B3: dp_seg visible

    // sweep: each negative thread scans the dense positive list per anchor
    float tot = 0.0f;
    int   cnt = 0;
    #pragma unroll
    for (int k = 0; k < APB; ++k) {
        if (isNeg[k]) {
            const float dk = d[k];
            const float* seg = dp_seg[k];
            const int    Pk  = P[k];
            #pragma unroll 4
            for (int p = 0; p < Pk; ++p) {
                const float term = 1.0f - (dk - seg[p]);   // 1 - (an - ap)
                if (term > 0.0f && term < 1.0f) { cnt += 1; tot += term; }
            }
        }
    }
    #pragma unroll
    for (int off = 32; off > 0; off >>= 1) {
        tot += __shfl_down(tot, off, 64);
        cnt += __shfl_down(cnt, off, 64);
    }
    if (lane == 0) { rf[wid] = tot; ri[wid] = cnt; }
    __syncthreads();                       // B4
    if (t == 0) {
        float T = 0.0f; int C = 0;
        #pragma unroll
        for (int w = 0; w < 6; ++w) { T += rf[w]; C += ri[w]; }
        part_T[i * PSTRIDE + b] = T;
        part_C[i * PSTRIDE + b] = C;
    }
}

// ---------------------------------------------------------------------------
// Kernel 2: 384 threads; 128-thread group per loss. 1 barrier, 4 outputs.
// ---------------------------------------------------------------------------
__global__ __launch_bounds__(384) void finalize_kernel(
    const float* __restrict__ part_T,
    const int*   __restrict__ part_C,
    float* __restrict__ out)
{
    const int t    = threadIdx.x;
    const int lane = t & 63;
    const int wid  = t >> 6;
    const int i    = t >> 7;       // 0..2
    const int b    = t & 127;
    __shared__ float rf[6];
    __shared__ int   ri[6];

    float T = (b < BPI) ? part_T[i * PSTRIDE + b] : 0.0f;
    int   C = (b < BPI) ? part_C[i * PSTRIDE + b] : 0;
    #pragma unroll
    for (int off = 32; off > 0; off >>= 1) {
        T += __shfl_down(T, off, 64);
        C += __shfl_down(C, off, 64);
    }
    if (lane == 0) { rf[wid] = T; ri[wid] = C; }
    __syncthreads();
    if (t == 0) {
        float lsum = 0.0f;
        #pragma unroll
        for (int j = 0; j < NI; ++j) {
            const float Tj = rf[2 * j] + rf[2 * j + 1];
            const int   Cj = ri[2 * j] + ri[2 * j + 1];
            const float lj = (Cj > 0) ? (Tj / (float)Cj) : 0.0f;
            out[1 + j] = lj;
            lsum += lj;
        }
        out[0] = lsum;
    }
}

extern "C" void kernel_launch(void* const* d_in, const int* in_sizes, int n_in,
                              void* d_out, int out_size, void* d_ws, size_t ws_size,
                              hipStream_t stream) {
    const float* vr         = (const float*)d_in[1];
    const float* target     = (const float*)d_in[2];
    const int*   label_item = (const int*)d_in[4];
    float* out = (float*)d_out;

    float* part_T = (float*)d_ws;                  // NI*PSTRIDE floats
    int*   part_C = (int*)(part_T + NI * PSTRIDE); // NI*PSTRIDE ints

    triplet_kernel<<<GRID, 384, 0, stream>>>(vr, target, label_item,
                                             part_T, part_C);
    finalize_kernel<<<1, 384, 0, stream>>>(part_T, part_C, out);
}